// Round 2
// baseline (851.721 us; speedup 1.0000x reference)
//
#include <hip/hip_runtime.h>
#include <hip/hip_bf16.h>
#include <cstdint>

// Set2Set forward, 3 steps. N=200000, B=1024 segments, D=256. All f32 I/O.
// Round 8: SINGLE persistent kernel. 512 blocks x 256 threads, guaranteed
// co-resident (launch_bounds(256,2) => 2 blocks/CU x 256 CU = 512), with a
// hand-rolled agent-scope grid barrier (6 barriers replace 6 launch
// boundaries). Tests the theory that the stable ~250us gap between the
// bottom-up roofline (~170us) and measured 425us is dispatch-structure
// overhead, not in-kernel time. c and LSTM bias now live in registers;
// GEMM keeps the exact per-lane MFMA accumulation order of round 7
// (bitwise-identical gates). Attn streaming loop unchanged from round 7.

#define NN     200000
#define BSEG   1024
#define DD     256
#define KA     512     // collapsed K
#define FOURD  1024
#define NBLK   512

using bf16x8 = __attribute__((ext_vector_type(8))) __bf16;
using f32x4  = __attribute__((ext_vector_type(4))) float;

__device__ __forceinline__ float bf2f(unsigned int u) {
  union { unsigned int i; float f; } v; v.i = (u & 0xffffu) << 16; return v.f;
}
__device__ __forceinline__ unsigned short f2bf(float f) {
  union { float f; unsigned int i; } v; v.f = f;
  unsigned int x = v.i;
  if ((x & 0x7fffffffu) > 0x7f800000u) return (unsigned short)((x >> 16) | 0x40);
  return (unsigned short)((x + 0x7fffu + ((x >> 16) & 1u)) >> 16);
}
__device__ __forceinline__ void split_bf(float f, unsigned short& hi, unsigned short& lo) {
  hi = f2bf(f);
  lo = f2bf(f - bf2f(hi));
}

// Sense-free generation grid barrier. bar[0]=arrive count, bar[1]=generation.
// All NBLK blocks are co-resident (launch bounds guarantee), so no deadlock.
__device__ __forceinline__ void grid_barrier(int* bar, int& gen) {
  __syncthreads();
  if (threadIdx.x == 0) {
    __threadfence();                 // agent-scope release of this phase's writes
    gen++;
    int prev = __hip_atomic_fetch_add(&bar[0], 1, __ATOMIC_ACQ_REL,
                                      __HIP_MEMORY_SCOPE_AGENT);
    if (prev == NBLK - 1) {
      __hip_atomic_store(&bar[0], 0, __ATOMIC_RELAXED, __HIP_MEMORY_SCOPE_AGENT);
      __hip_atomic_fetch_add(&bar[1], 1, __ATOMIC_RELEASE,
                             __HIP_MEMORY_SCOPE_AGENT);
    } else {
      while (__hip_atomic_load(&bar[1], __ATOMIC_ACQUIRE,
                               __HIP_MEMORY_SCOPE_AGENT) < gen)
        __builtin_amdgcn_s_sleep(2);
    }
  }
  __syncthreads();
}

// Load a 4-row group starting at `base` (addresses clamped to tend-1;
// clamped rows are masked to weight 0 in PROC). Requires base < tend.
#define LDG(buf, base) do {                                                 \
    int r0_ = (base);                                                       \
    int r1_ = (base) + 1 < tend ? (base) + 1 : tend - 1;                    \
    int r2_ = (base) + 2 < tend ? (base) + 2 : tend - 1;                    \
    int r3_ = (base) + 3 < tend ? (base) + 3 : tend - 1;                    \
    buf[0] = *(const float4*)(x + (size_t)r0_ * DD + lane * 4);             \
    buf[1] = *(const float4*)(x + (size_t)r1_ * DD + lane * 4);             \
    buf[2] = *(const float4*)(x + (size_t)r2_ * DD + lane * 4);             \
    buf[3] = *(const float4*)(x + (size_t)r3_ * DD + lane * 4);             \
  } while (0)

#define PROC(buf, base) do {                                                \
    float dx_ = buf[0].x*q.x + buf[0].y*q.y + buf[0].z*q.z + buf[0].w*q.w;  \
    float dy_ = buf[1].x*q.x + buf[1].y*q.y + buf[1].z*q.z + buf[1].w*q.w;  \
    float dz_ = buf[2].x*q.x + buf[2].y*q.y + buf[2].z*q.z + buf[2].w*q.w;  \
    float dw_ = buf[3].x*q.x + buf[3].y*q.y + buf[3].z*q.z + buf[3].w*q.w;  \
    _Pragma("unroll")                                                       \
    for (int off_ = 32; off_; off_ >>= 1) {                                 \
      dx_ += __shfl_xor(dx_, off_);                                         \
      dy_ += __shfl_xor(dy_, off_);                                         \
      dz_ += __shfl_xor(dz_, off_);                                         \
      dw_ += __shfl_xor(dw_, off_);                                         \
    }                                                                       \
    if ((base) + 1 >= tend) dy_ = -3.402823466e38f;                         \
    if ((base) + 2 >= tend) dz_ = -3.402823466e38f;                         \
    if ((base) + 3 >= tend) dw_ = -3.402823466e38f;                         \
    float mn_ = fmaxf(fmaxf(fmaxf(dx_, dy_), fmaxf(dz_, dw_)), m);          \
    float al_ = __expf(m - mn_);                                            \
    float w0_ = __expf(dx_ - mn_), w1_ = __expf(dy_ - mn_);                 \
    float w2_ = __expf(dz_ - mn_), w3_ = __expf(dw_ - mn_);                 \
    l = l * al_ + (w0_ + w1_) + (w2_ + w3_);                                \
    v.x = (v.x*al_ + w0_*buf[0].x) + (w1_*buf[1].x + w2_*buf[2].x) + w3_*buf[3].x; \
    v.y = (v.y*al_ + w0_*buf[0].y) + (w1_*buf[1].y + w2_*buf[2].y) + w3_*buf[3].y; \
    v.z = (v.z*al_ + w0_*buf[0].z) + (w1_*buf[1].z + w2_*buf[2].z) + w3_*buf[3].z; \
    v.w = (v.w*al_ + w0_*buf[0].w) + (w1_*buf[1].w + w2_*buf[2].w) + w3_*buf[3].w; \
    m = mn_;                                                                \
  } while (0)

__global__ __launch_bounds__(256, 2) void set2set_all(
    const float* __restrict__ x, const int* __restrict__ batch,
    const float* __restrict__ qst, const float* __restrict__ Wih,
    const float* __restrict__ Whh, const float* __restrict__ bih,
    const float* __restrict__ bhh,
    int* __restrict__ segs,
    unsigned short* __restrict__ W1hi, unsigned short* __restrict__ W1lo,
    unsigned short* __restrict__ W2hi, unsigned short* __restrict__ W2lo,
    unsigned short* __restrict__ Ahi, unsigned short* __restrict__ Alo,
    float* __restrict__ gates, int* __restrict__ bar,
    float* __restrict__ qout) {
  int k = blockIdx.x, t = threadIdx.x;
  int w = t >> 6, lane = t & 63;
  int r16 = lane & 15, quad = lane >> 4;
  int gen = 0;

  // ---------------- prep phase (replaces prep_all) ----------------
  int g = k * 256 + t;                       // 0..131071
  #pragma unroll
  for (int rep = 0; rep < 4; ++rep) {
    int idx = g + rep * (NBLK * 256);        // covers 524288 = 1024*512
    int j = idx >> 9, kk = idx & 511;
    float w1 = Wih[idx];
    float w2 = (kk < 256) ? w1 + Whh[j * 256 + kk] : w1;
    unsigned short hi, lo;
    split_bf(w1, hi, lo); W1hi[idx] = hi; W1lo[idx] = lo;
    split_bf(w2, hi, lo); W2hi[idx] = hi; W2lo[idx] = lo;
    float a = qst[idx];
    split_bf(a, hi, lo); Ahi[idx] = hi; Alo[idx] = lo;
  }
  if (g <= BSEG) {
    int lo = 0, hi = NN;
    while (lo < hi) { int mid = (lo + hi) >> 1; if (batch[mid] < g) lo = mid + 1; else hi = mid; }
    segs[g] = lo;
  }
  // LSTM bias for channel t, all 4 gates — constant across steps, registers.
  float bi0 = bih[t]       + bhh[t];
  float bi1 = bih[256 + t] + bhh[256 + t];
  float bi2 = bih[512 + t] + bhh[512 + t];
  float bi3 = bih[768 + t] + bhh[768 + t];

  grid_barrier(bar, gen);

  // segment bounds for this block's two segments (2k, 2k+1)
  int s0 = segs[2 * k], e0 = segs[2 * k + 1], e1 = segs[2 * k + 2];

  // GEMM tile geometry: tiles T=2k, 2k+1 (adjacent n-tiles share A rows).
  int m0 = (k >> 4) << 5;                    // 32-row band
  int n0 = (k & 15) << 6;                    // 64-col band (two 32-tiles)
  int arow = m0 + ((w >> 1) << 4) + r16;     // A row for this lane's frags
  int bcol = n0 + ((w & 1) << 4) + r16;      // W row (gate col), tile 0

  __shared__ __align__(16) float sh[DD];
  __shared__ float sm[4], sl[4];
  __shared__ __align__(16) float sv[4][DD];

  float c0 = 0.f, c1 = 0.f;                  // LSTM cell state, in registers

  for (int step = 0; step < 3; ++step) {
    const unsigned short* Whi_ = step ? W2hi : W1hi;
    const unsigned short* Wlo_ = step ? W2lo : W1lo;

    // ---------------- GEMM phase: gates = (Ahi+Alo) @ (Whi+Wlo)^T ----------
    {
      const unsigned short* ah  = Ahi  + (size_t)arow * KA + quad * 8;
      const unsigned short* al  = Alo  + (size_t)arow * KA + quad * 8;
      const unsigned short* b0h = Whi_ + (size_t)bcol * KA + quad * 8;
      const unsigned short* b0l = Wlo_ + (size_t)bcol * KA + quad * 8;
      const unsigned short* b1h = b0h + (size_t)32 * KA;
      const unsigned short* b1l = b0l + (size_t)32 * KA;
      f32x4 acc0 = {}, acc1 = {};
      #pragma unroll 4
      for (int kk = 0; kk < 16; ++kk) {      // chunk = kk*32 + quad*8 (same order as r7)
        bf16x8 a  = *(const bf16x8*)(ah  + kk * 32);
        bf16x8 aL = *(const bf16x8*)(al  + kk * 32);
        bf16x8 bh = *(const bf16x8*)(b0h + kk * 32);
        bf16x8 bl = *(const bf16x8*)(b0l + kk * 32);
        bf16x8 ch = *(const bf16x8*)(b1h + kk * 32);
        bf16x8 cl = *(const bf16x8*)(b1l + kk * 32);
        acc0 = __builtin_amdgcn_mfma_f32_16x16x32_bf16(a,  bh, acc0, 0, 0, 0);
        acc0 = __builtin_amdgcn_mfma_f32_16x16x32_bf16(a,  bl, acc0, 0, 0, 0);
        acc0 = __builtin_amdgcn_mfma_f32_16x16x32_bf16(aL, bh, acc0, 0, 0, 0);
        acc1 = __builtin_amdgcn_mfma_f32_16x16x32_bf16(a,  ch, acc1, 0, 0, 0);
        acc1 = __builtin_amdgcn_mfma_f32_16x16x32_bf16(a,  cl, acc1, 0, 0, 0);
        acc1 = __builtin_amdgcn_mfma_f32_16x16x32_bf16(aL, ch, acc1, 0, 0, 0);
      }
      int orow = m0 + ((w >> 1) << 4) + (quad << 2);
      int ocol = n0 + ((w & 1) << 4) + r16;
      #pragma unroll
      for (int r = 0; r < 4; ++r) {
        gates[(size_t)(orow + r) * FOURD + ocol]      = acc0[r];
        gates[(size_t)(orow + r) * FOURD + ocol + 32] = acc1[r];
      }
    }
    grid_barrier(bar, gen);                  // gates complete

    // ---------------- attn phase: segments 2k and 2k+1 ---------------------
    #pragma unroll
    for (int j = 0; j < 2; ++j) {
      int b = 2 * k + j;
      const float* gg_ = gates + (size_t)b * FOURD;
      float gi = gg_[t]       + bi0;
      float gf = gg_[256 + t] + bi1;
      float gg = gg_[512 + t] + bi2;
      float go = gg_[768 + t] + bi3;
      float ig = 1.f / (1.f + expf(-gi));
      float fg = 1.f / (1.f + expf(-gf));
      float gt = tanhf(gg);
      float og = 1.f / (1.f + expf(-go));
      float cn = fg * (j ? c1 : c0) + ig * gt;
      if (j) c1 = cn; else c0 = cn;
      float hn = og * tanhf(cn);

      __syncthreads();                       // protect sh/sv reuse across j
      sh[t] = hn;
      {
        unsigned short hi, lo; split_bf(hn, hi, lo);
        size_t ro = (size_t)b * KA;
        Ahi[ro + t] = hi;  Alo[ro + t] = lo;
        qout[(size_t)b * 512 + t] = hn;
      }
      __syncthreads();

      int s = j ? e0 : s0, tend = j ? e1 : e0;
      float4 q = *(const float4*)(sh + lane * 4);
      float m = -3.402823466e38f;
      float l = 0.f;
      float4 v = {0.f, 0.f, 0.f, 0.f};

      int i0 = s + w * 4;
      float4 b0[4], b1[4], b2[4];
      if (i0      < tend) LDG(b0, i0);
      if (i0 + 16 < tend) LDG(b1, i0 + 16);
      if (i0 + 32 < tend) LDG(b2, i0 + 32);
      for (int i = i0; i < tend; i += 48) {
        PROC(b0, i);
        if (i + 48 < tend) LDG(b0, i + 48);
        if (i + 16 < tend) {
          PROC(b1, i + 16);
          if (i + 64 < tend) LDG(b1, i + 64);
          if (i + 32 < tend) {
            PROC(b2, i + 32);
            if (i + 80 < tend) LDG(b2, i + 80);
          }
        }
      }

      if (lane == 0) { sm[w] = m; sl[w] = l; }
      *(float4*)(&sv[w][lane * 4]) = v;
      __syncthreads();

      float M = fmaxf(fmaxf(sm[0], sm[1]), fmaxf(sm[2], sm[3]));
      if (M < -1e37f) M = 0.f;               // mirror reference isfinite guard
      float a0 = __expf(sm[0] - M), a1 = __expf(sm[1] - M);
      float a2 = __expf(sm[2] - M), a3 = __expf(sm[3] - M);
      float L = sl[0] * a0 + sl[1] * a1 + sl[2] * a2 + sl[3] * a3;
      float r = (sv[0][t] * a0 + sv[1][t] * a1 + sv[2][t] * a2 + sv[3][t] * a3)
                / (L + 1e-16f);

      unsigned short hi, lo; split_bf(r, hi, lo);
      size_t ro = (size_t)b * KA;
      Ahi[ro + DD + t] = hi;  Alo[ro + DD + t] = lo;
      qout[(size_t)b * 512 + DD + t] = r;
    }
    if (step < 2) grid_barrier(bar, gen);    // A ready for next GEMM
  }
}

// ---- launch --------------------------------------------------------------
extern "C" void kernel_launch(void* const* d_in, const int* in_sizes, int n_in,
                              void* d_out, int out_size, void* d_ws, size_t ws_size,
                              hipStream_t stream) {
  const float* x    = (const float*)d_in[0];
  const int*   batc = (const int*)d_in[2];
  const float* qst  = (const float*)d_in[3];
  const float* Wih  = (const float*)d_in[4];
  const float* Whh  = (const float*)d_in[5];
  const float* bih  = (const float*)d_in[6];
  const float* bhh  = (const float*)d_in[7];
  float* out = (float*)d_out;

  char* ws = (char*)d_ws;
  size_t off = 0;
  auto alloc = [&](size_t bytes) -> void* {
    void* p = ws + off; off = (off + bytes + 255) & ~(size_t)255; return p;
  };
  int*            bar  = (int*)alloc(256);
  int*            segs = (int*)alloc((size_t)(BSEG + 1) * 4);
  unsigned short* W1hi = (unsigned short*)alloc((size_t)FOURD * KA * 2);
  unsigned short* W1lo = (unsigned short*)alloc((size_t)FOURD * KA * 2);
  unsigned short* W2hi = (unsigned short*)alloc((size_t)FOURD * KA * 2);
  unsigned short* W2lo = (unsigned short*)alloc((size_t)FOURD * KA * 2);
  unsigned short* Ahi  = (unsigned short*)alloc((size_t)BSEG * KA * 2);
  unsigned short* Alo  = (unsigned short*)alloc((size_t)BSEG * KA * 2);
  float*          gate = (float*)alloc((size_t)BSEG * FOURD * 4);

  hipMemsetAsync(bar, 0, 2 * sizeof(int), stream);
  set2set_all<<<NBLK, 256, 0, stream>>>(
      x, batc, qst, Wih, Whh, bih, bhh,
      segs, W1hi, W1lo, W2hi, W2lo, Ahi, Alo, gate, bar, out);
}

// Round 3
// 637.589 us; speedup vs baseline: 1.3358x; 1.3358x over previous
//
#include <hip/hip_runtime.h>
#include <hip/hip_bf16.h>
#include <cstdint>

// Set2Set forward, 3 steps. N=200000, B=1024 segments, D=256. All f32 I/O.
// Round 9: back to 7-dispatch structure (r8 proved fusion/launch overhead
// was NOT the cost; harness has ~200us fixed floor). Attention rebuilt as a
// two-pass LDS-tile kernel to kill the per-row 6-level shfl_xor chain that
// saturated the per-CU LDS pipe (r8's wave-count scaling evidence):
//   - 32-row x-tile staged in LDS, XOR-swizzled (j ^= 4*(i&7)), uniform
//     bank load (b128 baseline) for write, dot-read and sweep-read.
//   - dot pass: 8 lanes/row -> 3 shfl levels per 8 rows (was 6 per 4 rows).
//   - tile max: 5 shfl per 32 rows; weights recomputed inline (broadcast).
//   - v-sweep: per wave 8 rows, 1 b128 + 4 fma each; per-wave (m,l,v)
//     merged at the end (same merge code as before).
//   - T14 async-stage: next tile's global loads issued before current
//     tile's compute. 4 blocks/CU (launch_bounds(256,4), ~38 KB LDS).
// GEMM (K=512 collapsed, XOR-swizzled LDS W staging, bf16 hi/lo
// compensated 3-mfma) and prep verbatim from round 6/7.

#define NN     200000
#define BSEG   1024
#define DD     256
#define KA     512     // collapsed K
#define FOURD  1024

using bf16x8 = __attribute__((ext_vector_type(8))) __bf16;
using f32x4  = __attribute__((ext_vector_type(4))) float;

__device__ __forceinline__ float bf2f(unsigned int u) {
  union { unsigned int i; float f; } v; v.i = (u & 0xffffu) << 16; return v.f;
}
__device__ __forceinline__ unsigned short f2bf(float f) {
  union { float f; unsigned int i; } v; v.f = f;
  unsigned int x = v.i;
  if ((x & 0x7fffffffu) > 0x7f800000u) return (unsigned short)((x >> 16) | 0x40);
  return (unsigned short)((x + 0x7fffu + ((x >> 16) & 1u)) >> 16);
}
__device__ __forceinline__ void split_bf(float f, unsigned short& hi, unsigned short& lo) {
  hi = f2bf(f);
  lo = f2bf(f - bf2f(hi));
}

// ---- combined prep: seg bounds + W1/W2 split + A init + c=0 --------------
__global__ void prep_all(const int* __restrict__ batch, int* __restrict__ segs,
                         const float* __restrict__ Wih, const float* __restrict__ Whh,
                         const float* __restrict__ bih, const float* __restrict__ bhh,
                         unsigned short* __restrict__ W1hi, unsigned short* __restrict__ W1lo,
                         unsigned short* __restrict__ W2hi, unsigned short* __restrict__ W2lo,
                         float* __restrict__ bias,
                         const float* __restrict__ qst,
                         unsigned short* __restrict__ Ahi, unsigned short* __restrict__ Alo,
                         float* __restrict__ c) {
  int idx = blockIdx.x * 256 + threadIdx.x;       // grid covers 524288
  if (idx <= BSEG) {
    int lo = 0, hi = NN;
    while (lo < hi) { int mid = (lo + hi) >> 1; if (batch[mid] < idx) lo = mid + 1; else hi = mid; }
    segs[idx] = lo;
  }
  if (idx < FOURD) bias[idx] = bih[idx] + bhh[idx];
  if (idx < FOURD * KA) {
    int j = idx / KA, k = idx - j * KA;
    float w1 = Wih[j * 512 + k];
    float w2 = (k < 256) ? (Wih[j * 512 + k] + Whh[j * 256 + k])
                         : Wih[j * 512 + k];
    unsigned short hi, lo;
    split_bf(w1, hi, lo); W1hi[idx] = hi; W1lo[idx] = lo;
    split_bf(w2, hi, lo); W2hi[idx] = hi; W2lo[idx] = lo;
  }
  if (idx < BSEG * KA) {
    unsigned short hi, lo; split_bf(qst[idx], hi, lo);
    Ahi[idx] = hi; Alo[idx] = lo;
  }
  if (idx < BSEG * DD) c[idx] = 0.f;
}

// ---- LSTM gates GEMM: gates = (Ahi+Alo) @ (Whi+Wlo)^T, K=512 -------------
// 256 blocks, each 128 rows x 32 cols. W chunk (32 x 64k, hi+lo) staged in
// LDS with XOR swizzle; A read direct from global. (Verbatim round 6/7.)
__global__ __launch_bounds__(256) void gemm_gates(const unsigned short* __restrict__ Ahi,
                                                  const unsigned short* __restrict__ Alo,
                                                  const unsigned short* __restrict__ Whi,
                                                  const unsigned short* __restrict__ Wlo,
                                                  float* __restrict__ gates) {
  int bx = blockIdx.x;
  int m0 = (bx >> 5) << 7;      // * 128
  int n0 = (bx & 31) << 5;      // * 32
  int t = threadIdx.x, w = t >> 6, lane = t & 63;
  int r16 = lane & 15, quad = lane >> 4;

  __shared__ unsigned short sWhi[32 * 64];
  __shared__ unsigned short sWlo[32 * 64];

  f32x4 acc[2][2] = {};

  const unsigned short* a0h = Ahi + (size_t)(m0 + 32 * w + r16) * KA + quad * 8;
  const unsigned short* a0l = Alo + (size_t)(m0 + 32 * w + r16) * KA + quad * 8;

  int srow = t >> 3;            // 0..31
  int scb  = t & 7;             // 0..7 col-block (8 bf16 each)
  const unsigned short* gwh = Whi + (size_t)(n0 + srow) * KA + scb * 8;
  const unsigned short* gwl = Wlo + (size_t)(n0 + srow) * KA + scb * 8;
  int sdst = srow * 64 + ((scb ^ (srow & 7)) * 8);

  for (int kc = 0; kc < KA; kc += 64) {
    __syncthreads();
    *(bf16x8*)&sWhi[sdst] = *(const bf16x8*)(gwh + kc);
    *(bf16x8*)&sWlo[sdst] = *(const bf16x8*)(gwl + kc);
    __syncthreads();
    #pragma unroll
    for (int ks = 0; ks < 2; ++ks) {
      bf16x8 bh[2], bl[2];
      #pragma unroll
      for (int ni = 0; ni < 2; ++ni) {
        int wr = 16 * ni + r16;
        int off = wr * 64 + (((ks * 4 + quad) ^ (wr & 7)) * 8);
        bh[ni] = *(const bf16x8*)&sWhi[off];
        bl[ni] = *(const bf16x8*)&sWlo[off];
      }
      #pragma unroll
      for (int ms = 0; ms < 2; ++ms) {
        bf16x8 a  = *(const bf16x8*)(a0h + (size_t)ms * 16 * KA + kc + ks * 32);
        bf16x8 al = *(const bf16x8*)(a0l + (size_t)ms * 16 * KA + kc + ks * 32);
        #pragma unroll
        for (int ni = 0; ni < 2; ++ni) {
          acc[ms][ni] = __builtin_amdgcn_mfma_f32_16x16x32_bf16(a,  bh[ni], acc[ms][ni], 0, 0, 0);
          acc[ms][ni] = __builtin_amdgcn_mfma_f32_16x16x32_bf16(a,  bl[ni], acc[ms][ni], 0, 0, 0);
          acc[ms][ni] = __builtin_amdgcn_mfma_f32_16x16x32_bf16(al, bh[ni], acc[ms][ni], 0, 0, 0);
        }
      }
    }
  }
  #pragma unroll
  for (int ms = 0; ms < 2; ++ms)
    #pragma unroll
    for (int ni = 0; ni < 2; ++ni)
      #pragma unroll
      for (int r = 0; r < 4; ++r)
        gates[(size_t)(m0 + 32 * w + 16 * ms + quad * 4 + r) * FOURD
              + n0 + 16 * ni + r16] = acc[ms][ni][r];
}

// ---- fused LSTM-pointwise + two-pass LDS-tile online-softmax attention ---
// Block b handles segment b. Per 32-row tile:
//   pass L: coalesced global->reg (issued one tile ahead), swizzled reg->LDS
//   pass E: dot e_i = x_i . q  (8 lanes/row, 3 shfl levels)
//   merge:  tile max via 5 shfl, block-uniform online max m
//   pass V: per-wave rows i in {w, w+4, ...}: v += exp(se[i]-m) * x_i
// Per-wave (m,l,v) merged at the end (m is block-uniform; merge is exact).
__global__ __launch_bounds__(256, 4) void attn_fused(const float* __restrict__ x,
                                                     const int* __restrict__ segs,
                                                     const float* __restrict__ gates,
                                                     const float* __restrict__ bias,
                                                     float* __restrict__ c,
                                                     unsigned short* __restrict__ Ahi,
                                                     unsigned short* __restrict__ Alo,
                                                     float* __restrict__ qout) {
  int b = blockIdx.x, t = threadIdx.x;
  int w = t >> 6, lane = t & 63;

  // --- LSTM pointwise, channel t of row b (gate order i,f,g,o) ---
  const float* g = gates + (size_t)b * FOURD;
  float gi = g[t]       + bias[t];
  float gf = g[256 + t] + bias[256 + t];
  float gg = g[512 + t] + bias[512 + t];
  float go = g[768 + t] + bias[768 + t];
  float ig = 1.f / (1.f + expf(-gi));
  float fg = 1.f / (1.f + expf(-gf));
  float gt = tanhf(gg);
  float og = 1.f / (1.f + expf(-go));
  int cidx = b * DD + t;
  float cn = fg * c[cidx] + ig * gt;
  c[cidx] = cn;
  float hn = og * tanhf(cn);

  __shared__ float shq[DD];                 // q, XOR-swizzled for broadcast dot reads
  __shared__ __align__(16) float xt[32 * DD];
  __shared__ float se[32];
  __shared__ float sm[4], sl[4];
  __shared__ __align__(16) float sv[4][DD];

  shq[t ^ (4 * ((t >> 5) & 7))] = hn;       // involution on bits 2-4
  {
    unsigned short hi, lo; split_bf(hn, hi, lo);
    size_t ro = (size_t)b * KA;
    Ahi[ro + t] = hi;  Alo[ro + t] = lo;    // h-part [0,256)
    qout[(size_t)b * 512 + t] = hn;         // output q half
  }
  __syncthreads();

  // --- attention over segment b ---
  int s = segs[b], e = segs[b + 1];
  int r8 = lane >> 3, d8 = lane & 7;

  float m = -3.402823466e38f, l = 0.f;
  float4 v = {0.f, 0.f, 0.f, 0.f};          // cols 4*lane .. 4*lane+3 (wave copy)

  // prologue: load tile 0 into regs (coalesced: one full row per wave-instr)
  int R = e - s; if (R > 32) R = 32;        // <=0 if empty segment
  float4 st[8];
  #pragma unroll
  for (int k = 0; k < 8; ++k) {
    int i = w + 4 * k;
    if (i < R) st[k] = *(const float4*)(x + (size_t)(s + i) * DD + lane * 4);
  }

  for (int tb = s; tb < e; tb += 32) {
    __syncthreads();                        // xt/se free (prev tile consumed)
    #pragma unroll
    for (int k = 0; k < 8; ++k) {           // swizzled reg->LDS
      int i = w + 4 * k;
      if (i < R) *(float4*)&xt[i * DD + ((4 * lane) ^ (4 * (i & 7)))] = st[k];
    }
    __syncthreads();                        // xt ready

    // issue next tile's loads now; they fly under this tile's compute (T14)
    int Rn = e - (tb + 32); if (Rn > 32) Rn = 32;
    #pragma unroll
    for (int k = 0; k < 8; ++k) {
      int i = w + 4 * k;
      if (i < Rn) st[k] = *(const float4*)(x + (size_t)(tb + 32 + i) * DD + lane * 4);
    }

    // pass E: row i = 8w + r8, lane-chunk d8 covers words [32*d8, 32*d8+32)
    {
      int i = 8 * w + r8;
      int key = 4 * (i & 7);                // == 4*r8
      float4 acc = {0.f, 0.f, 0.f, 0.f};
      #pragma unroll
      for (int cc = 0; cc < 8; ++cc) {
        int j = d8 * 32 + 4 * cc;
        float4 xv = *(const float4*)&xt[i * DD + (j ^ key)];
        float4 qv = *(const float4*)&shq[j ^ (4 * d8)];   // broadcast read
        acc.x += xv.x * qv.x; acc.y += xv.y * qv.y;
        acc.z += xv.z * qv.z; acc.w += xv.w * qv.w;
      }
      float ee = (acc.x + acc.y) + (acc.z + acc.w);
      ee += __shfl_xor(ee, 1);
      ee += __shfl_xor(ee, 2);
      ee += __shfl_xor(ee, 4);
      if (i >= R) ee = -3.402823466e38f;    // mask garbage rows (after reduce)
      if (d8 == 0) se[i] = ee;
    }
    __syncthreads();                        // se ready

    // tile max (32 entries) -> block-uniform online max
    float tm = se[lane & 31];
    #pragma unroll
    for (int mask = 16; mask; mask >>= 1) tm = fmaxf(tm, __shfl_xor(tm, mask));
    float mn = fmaxf(m, tm);
    float alpha = __expf(m - mn);
    l *= alpha; v.x *= alpha; v.y *= alpha; v.z *= alpha; v.w *= alpha;

    // pass V: wave w sweeps rows {w, w+4, ..., w+28}
    #pragma unroll
    for (int k = 0; k < 8; ++k) {
      int i = w + 4 * k;
      if (i < R) {
        float wv = __expf(se[i] - mn);      // se[i] broadcast
        float4 xv = *(const float4*)&xt[i * DD + ((4 * lane) ^ (4 * (i & 7)))];
        l += wv;
        v.x += wv * xv.x; v.y += wv * xv.y; v.z += wv * xv.z; v.w += wv * xv.w;
      }
    }
    m = mn;
    R = Rn;
  }

  // --- merge 4 wave-partials (identical structure to round 7) ---
  if (lane == 0) { sm[w] = m; sl[w] = l; }
  *(float4*)(&sv[w][lane * 4]) = v;
  __syncthreads();

  float M = fmaxf(fmaxf(sm[0], sm[1]), fmaxf(sm[2], sm[3]));
  if (M < -1e37f) M = 0.f;                  // mirror reference isfinite guard
  float a0 = __expf(sm[0] - M), a1 = __expf(sm[1] - M);
  float a2 = __expf(sm[2] - M), a3 = __expf(sm[3] - M);
  float L = sl[0] * a0 + sl[1] * a1 + sl[2] * a2 + sl[3] * a3;
  float r = (sv[0][t] * a0 + sv[1][t] * a1 + sv[2][t] * a2 + sv[3][t] * a3)
            / (L + 1e-16f);

  unsigned short hi, lo; split_bf(r, hi, lo);
  size_t ro = (size_t)b * KA;
  Ahi[ro + DD + t] = hi;  Alo[ro + DD + t] = lo;   // r-part [256,512)
  qout[(size_t)b * 512 + DD + t] = r;              // output r half
}

// ---- launch --------------------------------------------------------------
extern "C" void kernel_launch(void* const* d_in, const int* in_sizes, int n_in,
                              void* d_out, int out_size, void* d_ws, size_t ws_size,
                              hipStream_t stream) {
  const float* x    = (const float*)d_in[0];
  const int*   batc = (const int*)d_in[2];
  const float* qst  = (const float*)d_in[3];
  const float* Wih  = (const float*)d_in[4];
  const float* Whh  = (const float*)d_in[5];
  const float* bih  = (const float*)d_in[6];
  const float* bhh  = (const float*)d_in[7];
  float* out = (float*)d_out;

  char* ws = (char*)d_ws;
  size_t off = 0;
  auto alloc = [&](size_t bytes) -> void* {
    void* p = ws + off; off = (off + bytes + 255) & ~(size_t)255; return p;
  };
  int*            segs = (int*)alloc((size_t)(BSEG + 1) * 4);
  unsigned short* W1hi = (unsigned short*)alloc((size_t)FOURD * KA * 2);
  unsigned short* W1lo = (unsigned short*)alloc((size_t)FOURD * KA * 2);
  unsigned short* W2hi = (unsigned short*)alloc((size_t)FOURD * KA * 2);
  unsigned short* W2lo = (unsigned short*)alloc((size_t)FOURD * KA * 2);
  unsigned short* Ahi  = (unsigned short*)alloc((size_t)BSEG * KA * 2);
  unsigned short* Alo  = (unsigned short*)alloc((size_t)BSEG * KA * 2);
  float*          gate = (float*)alloc((size_t)BSEG * FOURD * 4);
  float*          c    = (float*)alloc((size_t)BSEG * DD * 4);
  float*          bias = (float*)alloc((size_t)FOURD * 4);

  prep_all<<<(FOURD * KA + 255) / 256, 256, 0, stream>>>(
      batc, segs, Wih, Whh, bih, bhh, W1hi, W1lo, W2hi, W2lo, bias, qst, Ahi, Alo, c);

  for (int step = 0; step < 3; ++step) {
    const unsigned short* whi = step ? W2hi : W1hi;
    const unsigned short* wlo = step ? W2lo : W1lo;
    gemm_gates<<<256, 256, 0, stream>>>(Ahi, Alo, whi, wlo, gate);
    attn_fused<<<BSEG, 256, 0, stream>>>(x, segs, gate, bias, c, Ahi, Alo, out);
  }
}

// Round 4
// 620.693 us; speedup vs baseline: 1.3722x; 1.0272x over previous
//
#include <hip/hip_runtime.h>
#include <hip/hip_bf16.h>
#include <cstdint>

// Set2Set forward, 3 steps. N=200000, B=1024 segments, D=256. All f32 I/O.
// Round 10: r9 diagnosis — attn's st[8] prefetch buffer was spilled to
// scratch (VGPR=52 < 32 needed for st alone; WRITE_SIZE 204.9 MB/dispatch
// == sum-tiles x 32KB of spill writebacks). Cause: conditionally-defined
// st[k] (partial defs live across barriers/back-edge). Fix: ALL st[k]
// definitions unconditional with clamped row addresses (clamped duplicates
// are L2 hits, ~0 extra HBM). Consume-side masking unchanged -> identical
// arithmetic. Everything else verbatim from round 9.

#define NN     200000
#define BSEG   1024
#define DD     256
#define KA     512     // collapsed K
#define FOURD  1024

using bf16x8 = __attribute__((ext_vector_type(8))) __bf16;
using f32x4  = __attribute__((ext_vector_type(4))) float;

__device__ __forceinline__ float bf2f(unsigned int u) {
  union { unsigned int i; float f; } v; v.i = (u & 0xffffu) << 16; return v.f;
}
__device__ __forceinline__ unsigned short f2bf(float f) {
  union { float f; unsigned int i; } v; v.f = f;
  unsigned int x = v.i;
  if ((x & 0x7fffffffu) > 0x7f800000u) return (unsigned short)((x >> 16) | 0x40);
  return (unsigned short)((x + 0x7fffu + ((x >> 16) & 1u)) >> 16);
}
__device__ __forceinline__ void split_bf(float f, unsigned short& hi, unsigned short& lo) {
  hi = f2bf(f);
  lo = f2bf(f - bf2f(hi));
}

// ---- combined prep: seg bounds + W1/W2 split + A init + c=0 --------------
__global__ void prep_all(const int* __restrict__ batch, int* __restrict__ segs,
                         const float* __restrict__ Wih, const float* __restrict__ Whh,
                         const float* __restrict__ bih, const float* __restrict__ bhh,
                         unsigned short* __restrict__ W1hi, unsigned short* __restrict__ W1lo,
                         unsigned short* __restrict__ W2hi, unsigned short* __restrict__ W2lo,
                         float* __restrict__ bias,
                         const float* __restrict__ qst,
                         unsigned short* __restrict__ Ahi, unsigned short* __restrict__ Alo,
                         float* __restrict__ c) {
  int idx = blockIdx.x * 256 + threadIdx.x;       // grid covers 524288
  if (idx <= BSEG) {
    int lo = 0, hi = NN;
    while (lo < hi) { int mid = (lo + hi) >> 1; if (batch[mid] < idx) lo = mid + 1; else hi = mid; }
    segs[idx] = lo;
  }
  if (idx < FOURD) bias[idx] = bih[idx] + bhh[idx];
  if (idx < FOURD * KA) {
    int j = idx / KA, k = idx - j * KA;
    float w1 = Wih[j * 512 + k];
    float w2 = (k < 256) ? (Wih[j * 512 + k] + Whh[j * 256 + k])
                         : Wih[j * 512 + k];
    unsigned short hi, lo;
    split_bf(w1, hi, lo); W1hi[idx] = hi; W1lo[idx] = lo;
    split_bf(w2, hi, lo); W2hi[idx] = hi; W2lo[idx] = lo;
  }
  if (idx < BSEG * KA) {
    unsigned short hi, lo; split_bf(qst[idx], hi, lo);
    Ahi[idx] = hi; Alo[idx] = lo;
  }
  if (idx < BSEG * DD) c[idx] = 0.f;
}

// ---- LSTM gates GEMM: gates = (Ahi+Alo) @ (Whi+Wlo)^T, K=512 -------------
// (Verbatim round 6/7.)
__global__ __launch_bounds__(256) void gemm_gates(const unsigned short* __restrict__ Ahi,
                                                  const unsigned short* __restrict__ Alo,
                                                  const unsigned short* __restrict__ Whi,
                                                  const unsigned short* __restrict__ Wlo,
                                                  float* __restrict__ gates) {
  int bx = blockIdx.x;
  int m0 = (bx >> 5) << 7;      // * 128
  int n0 = (bx & 31) << 5;      // * 32
  int t = threadIdx.x, w = t >> 6, lane = t & 63;
  int r16 = lane & 15, quad = lane >> 4;

  __shared__ unsigned short sWhi[32 * 64];
  __shared__ unsigned short sWlo[32 * 64];

  f32x4 acc[2][2] = {};

  const unsigned short* a0h = Ahi + (size_t)(m0 + 32 * w + r16) * KA + quad * 8;
  const unsigned short* a0l = Alo + (size_t)(m0 + 32 * w + r16) * KA + quad * 8;

  int srow = t >> 3;            // 0..31
  int scb  = t & 7;             // 0..7 col-block (8 bf16 each)
  const unsigned short* gwh = Whi + (size_t)(n0 + srow) * KA + scb * 8;
  const unsigned short* gwl = Wlo + (size_t)(n0 + srow) * KA + scb * 8;
  int sdst = srow * 64 + ((scb ^ (srow & 7)) * 8);

  for (int kc = 0; kc < KA; kc += 64) {
    __syncthreads();
    *(bf16x8*)&sWhi[sdst] = *(const bf16x8*)(gwh + kc);
    *(bf16x8*)&sWlo[sdst] = *(const bf16x8*)(gwl + kc);
    __syncthreads();
    #pragma unroll
    for (int ks = 0; ks < 2; ++ks) {
      bf16x8 bh[2], bl[2];
      #pragma unroll
      for (int ni = 0; ni < 2; ++ni) {
        int wr = 16 * ni + r16;
        int off = wr * 64 + (((ks * 4 + quad) ^ (wr & 7)) * 8);
        bh[ni] = *(const bf16x8*)&sWhi[off];
        bl[ni] = *(const bf16x8*)&sWlo[off];
      }
      #pragma unroll
      for (int ms = 0; ms < 2; ++ms) {
        bf16x8 a  = *(const bf16x8*)(a0h + (size_t)ms * 16 * KA + kc + ks * 32);
        bf16x8 al = *(const bf16x8*)(a0l + (size_t)ms * 16 * KA + kc + ks * 32);
        #pragma unroll
        for (int ni = 0; ni < 2; ++ni) {
          acc[ms][ni] = __builtin_amdgcn_mfma_f32_16x16x32_bf16(a,  bh[ni], acc[ms][ni], 0, 0, 0);
          acc[ms][ni] = __builtin_amdgcn_mfma_f32_16x16x32_bf16(a,  bl[ni], acc[ms][ni], 0, 0, 0);
          acc[ms][ni] = __builtin_amdgcn_mfma_f32_16x16x32_bf16(al, bh[ni], acc[ms][ni], 0, 0, 0);
        }
      }
    }
  }
  #pragma unroll
  for (int ms = 0; ms < 2; ++ms)
    #pragma unroll
    for (int ni = 0; ni < 2; ++ni)
      #pragma unroll
      for (int r = 0; r < 4; ++r)
        gates[(size_t)(m0 + 32 * w + 16 * ms + quad * 4 + r) * FOURD
              + n0 + 16 * ni + r16] = acc[ms][ni][r];
}

// ---- fused LSTM-pointwise + two-pass LDS-tile online-softmax attention ---
__global__ __launch_bounds__(256, 4) void attn_fused(const float* __restrict__ x,
                                                     const int* __restrict__ segs,
                                                     const float* __restrict__ gates,
                                                     const float* __restrict__ bias,
                                                     float* __restrict__ c,
                                                     unsigned short* __restrict__ Ahi,
                                                     unsigned short* __restrict__ Alo,
                                                     float* __restrict__ qout) {
  int b = blockIdx.x, t = threadIdx.x;
  int w = t >> 6, lane = t & 63;

  // --- LSTM pointwise, channel t of row b (gate order i,f,g,o) ---
  const float* g = gates + (size_t)b * FOURD;
  float gi = g[t]       + bias[t];
  float gf = g[256 + t] + bias[256 + t];
  float gg = g[512 + t] + bias[512 + t];
  float go = g[768 + t] + bias[768 + t];
  float ig = 1.f / (1.f + expf(-gi));
  float fg = 1.f / (1.f + expf(-gf));
  float gt = tanhf(gg);
  float og = 1.f / (1.f + expf(-go));
  int cidx = b * DD + t;
  float cn = fg * c[cidx] + ig * gt;
  c[cidx] = cn;
  float hn = og * tanhf(cn);

  __shared__ float shq[DD];                 // q, XOR-swizzled for broadcast dot reads
  __shared__ __align__(16) float xt[32 * DD];
  __shared__ float se[32];
  __shared__ float sm[4], sl[4];
  __shared__ __align__(16) float sv[4][DD];

  shq[t ^ (4 * ((t >> 5) & 7))] = hn;       // involution on bits 2-4
  {
    unsigned short hi, lo; split_bf(hn, hi, lo);
    size_t ro = (size_t)b * KA;
    Ahi[ro + t] = hi;  Alo[ro + t] = lo;    // h-part [0,256)
    qout[(size_t)b * 512 + t] = hn;         // output q half
  }
  __syncthreads();

  // --- attention over segment b ---
  int s = segs[b], e = segs[b + 1];
  int r8 = lane >> 3, d8 = lane & 7;

  float m = -3.402823466e38f, l = 0.f;
  float4 v = {0.f, 0.f, 0.f, 0.f};          // cols 4*lane .. 4*lane+3 (wave copy)

  // prologue: UNCONDITIONAL clamped loads — st[] fully defined, stays in
  // VGPRs (r9's conditional defs spilled it to scratch: 200 MB writebacks).
  int R = e - s; if (R > 32) R = 32;        // <=0 if empty segment
  float4 st[8];
  #pragma unroll
  for (int k = 0; k < 8; ++k) {
    int i = w + 4 * k;
    int ic = i < R ? i : R - 1;
    if (ic < 0) ic = 0;
    int row = s + ic;
    if (row > NN - 1) row = NN - 1;         // empty trailing segment: s==NN
    st[k] = *(const float4*)(x + (size_t)row * DD + lane * 4);
  }

  for (int tb = s; tb < e; tb += 32) {
    __syncthreads();                        // xt/se free (prev tile consumed)
    #pragma unroll
    for (int k = 0; k < 8; ++k) {           // swizzled reg->LDS
      int i = w + 4 * k;
      if (i < R) *(float4*)&xt[i * DD + ((4 * lane) ^ (4 * (i & 7)))] = st[k];
    }
    __syncthreads();                        // xt ready

    // issue next tile's loads now (T14); unconditional clamped -> no scratch
    int base2 = tb + 32;
    int Rn = e - base2; if (Rn > 32) Rn = 32;
    #pragma unroll
    for (int k = 0; k < 8; ++k) {
      int i = w + 4 * k;
      int ic = i < Rn ? i : Rn - 1;
      if (ic < 0) ic = 0;
      int row = base2 + ic;
      if (row > NN - 1) row = NN - 1;
      st[k] = *(const float4*)(x + (size_t)row * DD + lane * 4);
    }

    // pass E: row i = 8w + r8, lane-chunk d8 covers words [32*d8, 32*d8+32)
    {
      int i = 8 * w + r8;
      int key = 4 * (i & 7);                // == 4*r8
      float4 acc = {0.f, 0.f, 0.f, 0.f};
      #pragma unroll
      for (int cc = 0; cc < 8; ++cc) {
        int j = d8 * 32 + 4 * cc;
        float4 xv = *(const float4*)&xt[i * DD + (j ^ key)];
        float4 qv = *(const float4*)&shq[j ^ (4 * d8)];   // broadcast read
        acc.x += xv.x * qv.x; acc.y += xv.y * qv.y;
        acc.z += xv.z * qv.z; acc.w += xv.w * qv.w;
      }
      float ee = (acc.x + acc.y) + (acc.z + acc.w);
      ee += __shfl_xor(ee, 1);
      ee += __shfl_xor(ee, 2);
      ee += __shfl_xor(ee, 4);
      if (i >= R) ee = -3.402823466e38f;    // mask garbage rows (after reduce)
      if (d8 == 0) se[i] = ee;
    }
    __syncthreads();                        // se ready

    // tile max (32 entries) -> block-uniform online max
    float tm = se[lane & 31];
    #pragma unroll
    for (int mask = 16; mask; mask >>= 1) tm = fmaxf(tm, __shfl_xor(tm, mask));
    float mn = fmaxf(m, tm);
    float alpha = __expf(m - mn);
    l *= alpha; v.x *= alpha; v.y *= alpha; v.z *= alpha; v.w *= alpha;

    // pass V: wave w sweeps rows {w, w+4, ..., w+28}
    #pragma unroll
    for (int k = 0; k < 8; ++k) {
      int i = w + 4 * k;
      if (i < R) {
        float wv = __expf(se[i] - mn);      // se[i] broadcast
        float4 xv = *(const float4*)&xt[i * DD + ((4 * lane) ^ (4 * (i & 7)))];
        l += wv;
        v.x += wv * xv.x; v.y += wv * xv.y; v.z += wv * xv.z; v.w += wv * xv.w;
      }
    }
    m = mn;
    R = Rn;
  }

  // --- merge 4 wave-partials ---
  if (lane == 0) { sm[w] = m; sl[w] = l; }
  *(float4*)(&sv[w][lane * 4]) = v;
  __syncthreads();

  float M = fmaxf(fmaxf(sm[0], sm[1]), fmaxf(sm[2], sm[3]));
  if (M < -1e37f) M = 0.f;                  // mirror reference isfinite guard
  float a0 = __expf(sm[0] - M), a1 = __expf(sm[1] - M);
  float a2 = __expf(sm[2] - M), a3 = __expf(sm[3] - M);
  float L = sl[0] * a0 + sl[1] * a1 + sl[2] * a2 + sl[3] * a3;
  float r = (sv[0][t] * a0 + sv[1][t] * a1 + sv[2][t] * a2 + sv[3][t] * a3)
            / (L + 1e-16f);

  unsigned short hi, lo; split_bf(r, hi, lo);
  size_t ro = (size_t)b * KA;
  Ahi[ro + DD + t] = hi;  Alo[ro + DD + t] = lo;   // r-part [256,512)
  qout[(size_t)b * 512 + DD + t] = r;              // output r half
}

// ---- launch --------------------------------------------------------------
extern "C" void kernel_launch(void* const* d_in, const int* in_sizes, int n_in,
                              void* d_out, int out_size, void* d_ws, size_t ws_size,
                              hipStream_t stream) {
  const float* x    = (const float*)d_in[0];
  const int*   batc = (const int*)d_in[2];
  const float* qst  = (const float*)d_in[3];
  const float* Wih  = (const float*)d_in[4];
  const float* Whh  = (const float*)d_in[5];
  const float* bih  = (const float*)d_in[6];
  const float* bhh  = (const float*)d_in[7];
  float* out = (float*)d_out;

  char* ws = (char*)d_ws;
  size_t off = 0;
  auto alloc = [&](size_t bytes) -> void* {
    void* p = ws + off; off = (off + bytes + 255) & ~(size_t)255; return p;
  };
  int*            segs = (int*)alloc((size_t)(BSEG + 1) * 4);
  unsigned short* W1hi = (unsigned short*)alloc((size_t)FOURD * KA * 2);
  unsigned short* W1lo = (unsigned short*)alloc((size_t)FOURD * KA * 2);
  unsigned short* W2hi = (unsigned short*)alloc((size_t)FOURD * KA * 2);
  unsigned short* W2lo = (unsigned short*)alloc((size_t)FOURD * KA * 2);
  unsigned short* Ahi  = (unsigned short*)alloc((size_t)BSEG * KA * 2);
  unsigned short* Alo  = (unsigned short*)alloc((size_t)BSEG * KA * 2);
  float*          gate = (float*)alloc((size_t)BSEG * FOURD * 4);
  float*          c    = (float*)alloc((size_t)BSEG * DD * 4);
  float*          bias = (float*)alloc((size_t)FOURD * 4);

  prep_all<<<(FOURD * KA + 255) / 256, 256, 0, stream>>>(
      batc, segs, Wih, Whh, bih, bhh, W1hi, W1lo, W2hi, W2lo, bias, qst, Ahi, Alo, c);

  for (int step = 0; step < 3; ++step) {
    const unsigned short* whi = step ? W2hi : W1hi;
    const unsigned short* wlo = step ? W2lo : W1lo;
    gemm_gates<<<256, 256, 0, stream>>>(Ahi, Alo, whi, wlo, gate);
    attn_fused<<<BSEG, 256, 0, stream>>>(x, segs, gate, bias, c, Ahi, Alo, out);
  }
}

// Round 5
// 428.897 us; speedup vs baseline: 1.9858x; 1.4472x over previous
//
#include <hip/hip_runtime.h>
#include <hip/hip_bf16.h>
#include <cstdint>

// Set2Set forward, 3 steps. N=200000, B=1024 segments, D=256. All f32 I/O.
// Round 11: r10 post-mortem — st[8] STILL in scratch (VGPR=56, WRITE 239MB).
// Mechanism: SROA runs before loop unrolling; st[k] with loop-variable k is
// a runtime-indexed alloca -> promotion fails -> permanent scratch (rule
// #20), independent of VGPR headroom. Fix: EIGHT NAMED float4 regs st0..st7
// with literal-index load/store macros (same pattern as r7's buf[0..3],
// which never spilled). Consumed arithmetic bit-identical to r10.
// Everything else verbatim from round 10.

#define NN     200000
#define BSEG   1024
#define DD     256
#define KA     512     // collapsed K
#define FOURD  1024

using bf16x8 = __attribute__((ext_vector_type(8))) __bf16;
using f32x4  = __attribute__((ext_vector_type(4))) float;

__device__ __forceinline__ float bf2f(unsigned int u) {
  union { unsigned int i; float f; } v; v.i = (u & 0xffffu) << 16; return v.f;
}
__device__ __forceinline__ unsigned short f2bf(float f) {
  union { float f; unsigned int i; } v; v.f = f;
  unsigned int x = v.i;
  if ((x & 0x7fffffffu) > 0x7f800000u) return (unsigned short)((x >> 16) | 0x40);
  return (unsigned short)((x + 0x7fffu + ((x >> 16) & 1u)) >> 16);
}
__device__ __forceinline__ void split_bf(float f, unsigned short& hi, unsigned short& lo) {
  hi = f2bf(f);
  lo = f2bf(f - bf2f(hi));
}

// ---- combined prep: seg bounds + W1/W2 split + A init + c=0 --------------
__global__ void prep_all(const int* __restrict__ batch, int* __restrict__ segs,
                         const float* __restrict__ Wih, const float* __restrict__ Whh,
                         const float* __restrict__ bih, const float* __restrict__ bhh,
                         unsigned short* __restrict__ W1hi, unsigned short* __restrict__ W1lo,
                         unsigned short* __restrict__ W2hi, unsigned short* __restrict__ W2lo,
                         float* __restrict__ bias,
                         const float* __restrict__ qst,
                         unsigned short* __restrict__ Ahi, unsigned short* __restrict__ Alo,
                         float* __restrict__ c) {
  int idx = blockIdx.x * 256 + threadIdx.x;       // grid covers 524288
  if (idx <= BSEG) {
    int lo = 0, hi = NN;
    while (lo < hi) { int mid = (lo + hi) >> 1; if (batch[mid] < idx) lo = mid + 1; else hi = mid; }
    segs[idx] = lo;
  }
  if (idx < FOURD) bias[idx] = bih[idx] + bhh[idx];
  if (idx < FOURD * KA) {
    int j = idx / KA, k = idx - j * KA;
    float w1 = Wih[j * 512 + k];
    float w2 = (k < 256) ? (Wih[j * 512 + k] + Whh[j * 256 + k])
                         : Wih[j * 512 + k];
    unsigned short hi, lo;
    split_bf(w1, hi, lo); W1hi[idx] = hi; W1lo[idx] = lo;
    split_bf(w2, hi, lo); W2hi[idx] = hi; W2lo[idx] = lo;
  }
  if (idx < BSEG * KA) {
    unsigned short hi, lo; split_bf(qst[idx], hi, lo);
    Ahi[idx] = hi; Alo[idx] = lo;
  }
  if (idx < BSEG * DD) c[idx] = 0.f;
}

// ---- LSTM gates GEMM: gates = (Ahi+Alo) @ (Whi+Wlo)^T, K=512 -------------
// (Verbatim round 6/7.)
__global__ __launch_bounds__(256) void gemm_gates(const unsigned short* __restrict__ Ahi,
                                                  const unsigned short* __restrict__ Alo,
                                                  const unsigned short* __restrict__ Whi,
                                                  const unsigned short* __restrict__ Wlo,
                                                  float* __restrict__ gates) {
  int bx = blockIdx.x;
  int m0 = (bx >> 5) << 7;      // * 128
  int n0 = (bx & 31) << 5;      // * 32
  int t = threadIdx.x, w = t >> 6, lane = t & 63;
  int r16 = lane & 15, quad = lane >> 4;

  __shared__ unsigned short sWhi[32 * 64];
  __shared__ unsigned short sWlo[32 * 64];

  f32x4 acc[2][2] = {};

  const unsigned short* a0h = Ahi + (size_t)(m0 + 32 * w + r16) * KA + quad * 8;
  const unsigned short* a0l = Alo + (size_t)(m0 + 32 * w + r16) * KA + quad * 8;

  int srow = t >> 3;            // 0..31
  int scb  = t & 7;             // 0..7 col-block (8 bf16 each)
  const unsigned short* gwh = Whi + (size_t)(n0 + srow) * KA + scb * 8;
  const unsigned short* gwl = Wlo + (size_t)(n0 + srow) * KA + scb * 8;
  int sdst = srow * 64 + ((scb ^ (srow & 7)) * 8);

  for (int kc = 0; kc < KA; kc += 64) {
    __syncthreads();
    *(bf16x8*)&sWhi[sdst] = *(const bf16x8*)(gwh + kc);
    *(bf16x8*)&sWlo[sdst] = *(const bf16x8*)(gwl + kc);
    __syncthreads();
    #pragma unroll
    for (int ks = 0; ks < 2; ++ks) {
      bf16x8 bh[2], bl[2];
      #pragma unroll
      for (int ni = 0; ni < 2; ++ni) {
        int wr = 16 * ni + r16;
        int off = wr * 64 + (((ks * 4 + quad) ^ (wr & 7)) * 8);
        bh[ni] = *(const bf16x8*)&sWhi[off];
        bl[ni] = *(const bf16x8*)&sWlo[off];
      }
      #pragma unroll
      for (int ms = 0; ms < 2; ++ms) {
        bf16x8 a  = *(const bf16x8*)(a0h + (size_t)ms * 16 * KA + kc + ks * 32);
        bf16x8 al = *(const bf16x8*)(a0l + (size_t)ms * 16 * KA + kc + ks * 32);
        #pragma unroll
        for (int ni = 0; ni < 2; ++ni) {
          acc[ms][ni] = __builtin_amdgcn_mfma_f32_16x16x32_bf16(a,  bh[ni], acc[ms][ni], 0, 0, 0);
          acc[ms][ni] = __builtin_amdgcn_mfma_f32_16x16x32_bf16(a,  bl[ni], acc[ms][ni], 0, 0, 0);
          acc[ms][ni] = __builtin_amdgcn_mfma_f32_16x16x32_bf16(al, bh[ni], acc[ms][ni], 0, 0, 0);
        }
      }
    }
  }
  #pragma unroll
  for (int ms = 0; ms < 2; ++ms)
    #pragma unroll
    for (int ni = 0; ni < 2; ++ni)
      #pragma unroll
      for (int r = 0; r < 4; ++r)
        gates[(size_t)(m0 + 32 * w + 16 * ms + quad * 4 + r) * FOURD
              + n0 + 16 * ni + r16] = acc[ms][ni][r];
}

// ---- fused LSTM-pointwise + two-pass LDS-tile online-softmax attention ---
// Staging buffer: NAMED registers st0..st7, literal-index macros (SROA-safe).
#define LD1(dst, kk, base, RR) do {                                         \
    int i_ = w + 4 * (kk);                                                  \
    int ic_ = i_ < (RR) ? i_ : (RR) - 1;                                    \
    if (ic_ < 0) ic_ = 0;                                                   \
    int row_ = (base) + ic_;                                                \
    if (row_ > NN - 1) row_ = NN - 1;                                       \
    dst = *(const float4*)(x + (size_t)row_ * DD + lane * 4);               \
  } while (0)

#define ST1(src, kk) do {                                                   \
    int i_ = w + 4 * (kk);                                                  \
    if (i_ < R) *(float4*)&xt[i_ * DD + ((4 * lane) ^ (4 * (i_ & 7)))] = src; \
  } while (0)

#define LDALL(base, RR) do {                                                \
    LD1(st0, 0, base, RR); LD1(st1, 1, base, RR);                           \
    LD1(st2, 2, base, RR); LD1(st3, 3, base, RR);                           \
    LD1(st4, 4, base, RR); LD1(st5, 5, base, RR);                           \
    LD1(st6, 6, base, RR); LD1(st7, 7, base, RR);                           \
  } while (0)

#define STALL() do {                                                        \
    ST1(st0, 0); ST1(st1, 1); ST1(st2, 2); ST1(st3, 3);                     \
    ST1(st4, 4); ST1(st5, 5); ST1(st6, 6); ST1(st7, 7);                     \
  } while (0)

__global__ __launch_bounds__(256, 4) void attn_fused(const float* __restrict__ x,
                                                     const int* __restrict__ segs,
                                                     const float* __restrict__ gates,
                                                     const float* __restrict__ bias,
                                                     float* __restrict__ c,
                                                     unsigned short* __restrict__ Ahi,
                                                     unsigned short* __restrict__ Alo,
                                                     float* __restrict__ qout) {
  int b = blockIdx.x, t = threadIdx.x;
  int w = t >> 6, lane = t & 63;

  // --- LSTM pointwise, channel t of row b (gate order i,f,g,o) ---
  const float* g = gates + (size_t)b * FOURD;
  float gi = g[t]       + bias[t];
  float gf = g[256 + t] + bias[256 + t];
  float gg = g[512 + t] + bias[512 + t];
  float go = g[768 + t] + bias[768 + t];
  float ig = 1.f / (1.f + expf(-gi));
  float fg = 1.f / (1.f + expf(-gf));
  float gt = tanhf(gg);
  float og = 1.f / (1.f + expf(-go));
  int cidx = b * DD + t;
  float cn = fg * c[cidx] + ig * gt;
  c[cidx] = cn;
  float hn = og * tanhf(cn);

  __shared__ float shq[DD];                 // q, XOR-swizzled for broadcast dot reads
  __shared__ __align__(16) float xt[32 * DD];
  __shared__ float se[32];
  __shared__ float sm[4], sl[4];
  __shared__ __align__(16) float sv[4][DD];

  shq[t ^ (4 * ((t >> 5) & 7))] = hn;       // involution on bits 2-4
  {
    unsigned short hi, lo; split_bf(hn, hi, lo);
    size_t ro = (size_t)b * KA;
    Ahi[ro + t] = hi;  Alo[ro + t] = lo;    // h-part [0,256)
    qout[(size_t)b * 512 + t] = hn;         // output q half
  }
  __syncthreads();

  // --- attention over segment b ---
  int s = segs[b], e = segs[b + 1];
  int r8 = lane >> 3, d8 = lane & 7;

  float m = -3.402823466e38f, l = 0.f;
  float4 v = {0.f, 0.f, 0.f, 0.f};          // cols 4*lane .. 4*lane+3 (wave copy)

  int R = e - s; if (R > 32) R = 32;        // <=0 if empty segment
  float4 st0, st1, st2, st3, st4, st5, st6, st7;
  LDALL(s, R);                              // prologue: tile 0 into regs

  for (int tb = s; tb < e; tb += 32) {
    __syncthreads();                        // xt/se free (prev tile consumed)
    STALL();                                // swizzled reg->LDS
    __syncthreads();                        // xt ready

    // issue next tile's loads now (T14); named regs -> guaranteed VGPRs
    int base2 = tb + 32;
    int Rn = e - base2; if (Rn > 32) Rn = 32;
    LDALL(base2, Rn);

    // pass E: row i = 8w + r8, lane-chunk d8 covers words [32*d8, 32*d8+32)
    {
      int i = 8 * w + r8;
      int key = 4 * (i & 7);                // == 4*r8
      float4 acc = {0.f, 0.f, 0.f, 0.f};
      #pragma unroll
      for (int cc = 0; cc < 8; ++cc) {
        int j = d8 * 32 + 4 * cc;
        float4 xv = *(const float4*)&xt[i * DD + (j ^ key)];
        float4 qv = *(const float4*)&shq[j ^ (4 * d8)];   // broadcast read
        acc.x += xv.x * qv.x; acc.y += xv.y * qv.y;
        acc.z += xv.z * qv.z; acc.w += xv.w * qv.w;
      }
      float ee = (acc.x + acc.y) + (acc.z + acc.w);
      ee += __shfl_xor(ee, 1);
      ee += __shfl_xor(ee, 2);
      ee += __shfl_xor(ee, 4);
      if (i >= R) ee = -3.402823466e38f;    // mask garbage rows (after reduce)
      if (d8 == 0) se[i] = ee;
    }
    __syncthreads();                        // se ready

    // tile max (32 entries) -> block-uniform online max
    float tm = se[lane & 31];
    #pragma unroll
    for (int mask = 16; mask; mask >>= 1) tm = fmaxf(tm, __shfl_xor(tm, mask));
    float mn = fmaxf(m, tm);
    float alpha = __expf(m - mn);
    l *= alpha; v.x *= alpha; v.y *= alpha; v.z *= alpha; v.w *= alpha;

    // pass V: wave w sweeps rows {w, w+4, ..., w+28} (reads LDS, not st)
    #pragma unroll
    for (int k = 0; k < 8; ++k) {
      int i = w + 4 * k;
      if (i < R) {
        float wv = __expf(se[i] - mn);      // se[i] broadcast
        float4 xv = *(const float4*)&xt[i * DD + ((4 * lane) ^ (4 * (i & 7)))];
        l += wv;
        v.x += wv * xv.x; v.y += wv * xv.y; v.z += wv * xv.z; v.w += wv * xv.w;
      }
    }
    m = mn;
    R = Rn;
  }

  // --- merge 4 wave-partials ---
  if (lane == 0) { sm[w] = m; sl[w] = l; }
  *(float4*)(&sv[w][lane * 4]) = v;
  __syncthreads();

  float M = fmaxf(fmaxf(sm[0], sm[1]), fmaxf(sm[2], sm[3]));
  if (M < -1e37f) M = 0.f;                  // mirror reference isfinite guard
  float a0 = __expf(sm[0] - M), a1 = __expf(sm[1] - M);
  float a2 = __expf(sm[2] - M), a3 = __expf(sm[3] - M);
  float L = sl[0] * a0 + sl[1] * a1 + sl[2] * a2 + sl[3] * a3;
  float r = (sv[0][t] * a0 + sv[1][t] * a1 + sv[2][t] * a2 + sv[3][t] * a3)
            / (L + 1e-16f);

  unsigned short hi, lo; split_bf(r, hi, lo);
  size_t ro = (size_t)b * KA;
  Ahi[ro + DD + t] = hi;  Alo[ro + DD + t] = lo;   // r-part [256,512)
  qout[(size_t)b * 512 + DD + t] = r;              // output r half
}

// ---- launch --------------------------------------------------------------
extern "C" void kernel_launch(void* const* d_in, const int* in_sizes, int n_in,
                              void* d_out, int out_size, void* d_ws, size_t ws_size,
                              hipStream_t stream) {
  const float* x    = (const float*)d_in[0];
  const int*   batc = (const int*)d_in[2];
  const float* qst  = (const float*)d_in[3];
  const float* Wih  = (const float*)d_in[4];
  const float* Whh  = (const float*)d_in[5];
  const float* bih  = (const float*)d_in[6];
  const float* bhh  = (const float*)d_in[7];
  float* out = (float*)d_out;

  char* ws = (char*)d_ws;
  size_t off = 0;
  auto alloc = [&](size_t bytes) -> void* {
    void* p = ws + off; off = (off + bytes + 255) & ~(size_t)255; return p;
  };
  int*            segs = (int*)alloc((size_t)(BSEG + 1) * 4);
  unsigned short* W1hi = (unsigned short*)alloc((size_t)FOURD * KA * 2);
  unsigned short* W1lo = (unsigned short*)alloc((size_t)FOURD * KA * 2);
  unsigned short* W2hi = (unsigned short*)alloc((size_t)FOURD * KA * 2);
  unsigned short* W2lo = (unsigned short*)alloc((size_t)FOURD * KA * 2);
  unsigned short* Ahi  = (unsigned short*)alloc((size_t)BSEG * KA * 2);
  unsigned short* Alo  = (unsigned short*)alloc((size_t)BSEG * KA * 2);
  float*          gate = (float*)alloc((size_t)BSEG * FOURD * 4);
  float*          c    = (float*)alloc((size_t)BSEG * DD * 4);
  float*          bias = (float*)alloc((size_t)FOURD * 4);

  prep_all<<<(FOURD * KA + 255) / 256, 256, 0, stream>>>(
      batc, segs, Wih, Whh, bih, bhh, W1hi, W1lo, W2hi, W2lo, bias, qst, Ahi, Alo, c);

  for (int step = 0; step < 3; ++step) {
    const unsigned short* whi = step ? W2hi : W1hi;
    const unsigned short* wlo = step ? W2lo : W1lo;
    gemm_gates<<<256, 256, 0, stream>>>(Ahi, Alo, whi, wlo, gate);
    attn_fused<<<BSEG, 256, 0, stream>>>(x, segs, gate, bias, c, Ahi, Alo, out);
  }
}